// Round 3
// baseline (243.908 us; speedup 1.0000x reference)
//
#include <hip/hip_runtime.h>
#include <stdint.h>

// Problem constants
constexpr int NB = 8;      // batch
constexpr int NS = 2048;   // nodes
constexpr int ND = 256;    // in dim
constexpr int NDO = 256;   // out dim
constexpr int NL = 8;      // labels
constexpr int NE = 32768;  // edges per batch
constexpr int NG = NS * NL;        // groups (t,l) per batch = 16384
constexpr int KH = NL * ND + 32;   // H row length = 2080 (2048 data + 8 cnt + 24 zero pad)

typedef __attribute__((ext_vector_type(8))) short bf16x8;
typedef __attribute__((ext_vector_type(4))) float f32x4;
typedef unsigned int u32;

__device__ __forceinline__ float bf2f(uint32_t u) {
    return __uint_as_float(u << 16);
}
__device__ __forceinline__ uint32_t f2bf(float f) {
    uint32_t x = __float_as_uint(f);
    return (x + 0x7fffu + ((x >> 16) & 1u)) >> 16;
}

// async global->LDS, 16B per lane; lds ptr must be wave-uniform (HW adds lane*16)
__device__ __forceinline__ void gl_lds16(const void* gptr, void* lptr) {
    __builtin_amdgcn_global_load_lds(
        (const __attribute__((address_space(1))) u32*)gptr,
        (__attribute__((address_space(3))) u32*)lptr, 16, 0, 0);
}

// ---- prep: convert x->bf16, build wt2 = [W;bias;0]^T bf16, zero counts ----
// wt2[o][k]: k<2048 -> W[k>>8][k&255][o]; k in [2048,2056) -> bias[k-2048][o]; else 0
__global__ void prep_kernel(const float* __restrict__ x, const float* __restrict__ W,
                            const float* __restrict__ bias,
                            ushort* __restrict__ xb, ushort* __restrict__ wt2,
                            int* __restrict__ counts) {
    int blk = blockIdx.x;
    int tid = threadIdx.x;
    if (blk < 4096) {                       // x f32 -> bf16, 4 elems/thread
        int i = blk * 256 + tid;            // < NB*NS*ND/4
        float4 v = ((const float4*)x)[i];
        ushort4 o;
        o.x = (ushort)f2bf(v.x); o.y = (ushort)f2bf(v.y);
        o.z = (ushort)f2bf(v.z); o.w = (ushort)f2bf(v.w);
        ((ushort4*)xb)[i] = o;
    } else if (blk < 4352) {                // wt2, one block per output column o
        int o = blk - 4096;                 // < 256
        for (int k = tid; k < KH; k += 256) {
            float v = 0.f;
            if (k < NL * ND) v = W[(size_t)k * NDO + o];
            else if (k < NL * ND + NL) v = bias[(k - NL * ND) * NDO + o];
            wt2[(size_t)o * KH + k] = (ushort)f2bf(v);
        }
    } else {                                // zero counts: 131072 ints, int4 stores
        int i = (blk - 4352) * 256 + tid;   // < 32768
        ((int4*)counts)[i] = make_int4(0, 0, 0, 0);
    }
}

// ---- histogram over (b, tgt, label) groups ----
__global__ void hist_kernel(const int* __restrict__ tgt, const int* __restrict__ lab,
                            int* __restrict__ counts) {
    int i = blockIdx.x * blockDim.x + threadIdx.x;   // < NB*NE
    int b = i >> 15;                                  // NE = 32768
    int g = b * NG + tgt[i] * NL + lab[i];
    atomicAdd(&counts[g], 1);
}

// ---- per-batch exclusive scan over 16384 group counters; also write H tail cols ----
__global__ void scan_kernel(const int* __restrict__ counts,
                            int* __restrict__ offsets, int* __restrict__ cursor,
                            ushort* __restrict__ H) {
    int b = blockIdx.x;
    int t = threadIdx.x;  // 256 threads, 64 counters each
    __shared__ int part[256];
    int base = b * NG + t * 64;
    int s = 0;
    for (int i = 0; i < 64; i++) s += counts[base + i];
    part[t] = s;
    __syncthreads();
    if (t == 0) {
        int run = 0;
        for (int i = 0; i < 256; i++) { int v = part[i]; part[i] = run; run += v; }
    }
    __syncthreads();
    int run = part[t];
    for (int i = 0; i < 64; i++) {
        offsets[base + i] = run;
        cursor[base + i] = run;
        run += counts[base + i];
    }
    // H tail: H[b][trow][2048+l] = bf16(cnt), [2056,2080) = 0  (bias folded as K-cols)
    for (int tt = 0; tt < 8; tt++) {
        int trow = t * 8 + tt;
        ushort vals[32] __attribute__((aligned(16)));
        for (int l = 0; l < NL; l++)
            vals[l] = (ushort)f2bf((float)counts[b * NG + trow * NL + l]);
        for (int l = NL; l < 32; l++) vals[l] = 0;
        ushort* dst = H + ((size_t)(b * NS + trow)) * KH + NL * ND;
        for (int q = 0; q < 4; q++) ((uint4*)dst)[q] = ((const uint4*)vals)[q];
    }
}

// ---- placement: counting-sort edge srcs by (tgt,label) group ----
__global__ void place_kernel(const int* __restrict__ tgt, const int* __restrict__ lab,
                             const int* __restrict__ esrc,
                             int* __restrict__ cursor, int* __restrict__ sorted) {
    int i = blockIdx.x * blockDim.x + threadIdx.x;   // < NB*NE
    int b = i >> 15;
    int g = b * NG + tgt[i] * NL + lab[i];
    int p = atomicAdd(&cursor[g], 1);
    sorted[b * NE + p] = esrc[i];
}

__device__ __forceinline__ void accum4(float4& a, uint2 v) {
    a.x += bf2f(v.x & 0xffffu);
    a.y += bf2f(v.x >> 16);
    a.z += bf2f(v.y & 0xffffu);
    a.w += bf2f(v.y >> 16);
}

// ---- aggregate: one wave per (b,t,l) group; H[b][t][l*256..] = sum of x[src] rows ----
// x rows come from the 8 MB bf16 copy -> L2/L3-served random reads.
__global__ __launch_bounds__(256) void aggregate_kernel(
    const ushort* __restrict__ xb,
    const int* __restrict__ counts, const int* __restrict__ offsets,
    const int* __restrict__ sorted, ushort* __restrict__ H) {
    int g = blockIdx.x * 4 + (threadIdx.x >> 6);     // < NB*NG
    int lane = threadIdx.x & 63;
    int b = g >> 14;                                  // NG = 16384
    int r = g & (NG - 1);
    int t = r >> 3, l = r & (NL - 1);

    int n = counts[g];
    int off = offsets[g];
    const int* srcs = sorted + (size_t)b * NE + off;
    const ushort* xbb = xb + (size_t)b * NS * ND;

    float4 a0 = {0.f, 0.f, 0.f, 0.f};
    float4 a1 = {0.f, 0.f, 0.f, 0.f};
    for (int base = 0; base < n; base += 64) {
        int m = n - base;
        if (m > 64) m = 64;
        int my = (lane < m) ? srcs[base + lane] : 0;  // lane-parallel index preload
        int k = 0;
        for (; k + 2 <= m; k += 2) {
            int s0 = __shfl(my, k);
            int s1 = __shfl(my, k + 1);
            uint2 v0 = ((const uint2*)(xbb + (size_t)s0 * ND))[lane];
            uint2 v1 = ((const uint2*)(xbb + (size_t)s1 * ND))[lane];
            accum4(a0, v0);
            accum4(a1, v1);
        }
        if (k < m) {
            int s0 = __shfl(my, k);
            uint2 v0 = ((const uint2*)(xbb + (size_t)s0 * ND))[lane];
            accum4(a0, v0);
        }
    }
    a0.x += a1.x; a0.y += a1.y; a0.z += a1.z; a0.w += a1.w;
    uint2 o;
    o.x = f2bf(a0.x) | (f2bf(a0.y) << 16);
    o.y = f2bf(a0.z) | (f2bf(a0.w) << 16);
    ((uint2*)(H + ((size_t)(b * NS + t)) * KH + l * ND))[lane] = o;
}

// ---- GEMM: out[m][o] = relu( H[m][:] @ wt2[o][:] ), M=16384, N=256, K=2080 ----
// 128x64 tile, 4 waves 2x2, each wave 4x2 MFMA 16x16x32 subtiles, m97 staging.
__global__ __launch_bounds__(256) void gemm_kernel(
    const ushort* __restrict__ H, const ushort* __restrict__ wt2,
    float* __restrict__ out) {
    int nb0 = blockIdx.x * 64;                 // N tile (4)
    int m0 = blockIdx.y * 128;                 // M tile (128)

    __shared__ ushort As[128 * 32];            // 8 KB
    __shared__ ushort Bs[64 * 32];             // 4 KB

    int tid = threadIdx.x;
    int lane = tid & 63;
    int wave = __builtin_amdgcn_readfirstlane(tid >> 6);
    int wm = wave & 1, wn = wave >> 1;
    int ln = lane & 15, quad = lane >> 4;

    f32x4 acc[4][2] = {};

    const ushort* Ag = H + (size_t)m0 * KH;
    const ushort* Bg = wt2 + (size_t)nb0 * KH;

    int ra0 = tid >> 2, ca = (tid & 3) << 3;   // chunk coords, pass 0
    int ra1 = ra0 + 64;                        // pass 1 (A only)

    for (int k0 = 0; k0 < KH; k0 += 32) {
        gl_lds16(Ag + (size_t)ra0 * KH + k0 + ca, &As[(wave * 64) * 8]);
        gl_lds16(Ag + (size_t)ra1 * KH + k0 + ca, &As[(256 + wave * 64) * 8]);
        gl_lds16(Bg + (size_t)ra0 * KH + k0 + ca, &Bs[(wave * 64) * 8]);
        __syncthreads();

        bf16x8 af[4], bfr[2];
        for (int i = 0; i < 4; i++)
            af[i] = *(const bf16x8*)&As[(wm * 64 + i * 16 + ln) * 32 + quad * 8];
        for (int j = 0; j < 2; j++)
            bfr[j] = *(const bf16x8*)&Bs[(wn * 32 + j * 16 + ln) * 32 + quad * 8];
        for (int i = 0; i < 4; i++)
            for (int j = 0; j < 2; j++)
                acc[i][j] = __builtin_amdgcn_mfma_f32_16x16x32_bf16(af[i], bfr[j], acc[i][j], 0, 0, 0);
        __syncthreads();
    }

    // epilogue: C/D layout col=lane&15, row=quad*4+r ; fused relu, f32 out
    for (int j = 0; j < 2; j++) {
        int col = nb0 + wn * 32 + j * 16 + ln;
        for (int i = 0; i < 4; i++) {
            int rbase = m0 + wm * 64 + i * 16 + quad * 4;
            for (int rr = 0; rr < 4; rr++) {
                out[(size_t)(rbase + rr) * NDO + col] = fmaxf(acc[i][j][rr], 0.f);
            }
        }
    }
}

extern "C" void kernel_launch(void* const* d_in, const int* in_sizes, int n_in,
                              void* d_out, int out_size, void* d_ws, size_t ws_size,
                              hipStream_t stream) {
    const float* x    = (const float*)d_in[0];
    const int*   esrc = (const int*)d_in[1];
    const int*   etgt = (const int*)d_in[2];
    const int*   elab = (const int*)d_in[3];
    const float* W    = (const float*)d_in[4];
    const float* bias = (const float*)d_in[5];
    float* out = (float*)d_out;

    char* ws = (char*)d_ws;
    ushort* xb     = (ushort*)(ws);                    //  8 MB: x bf16
    ushort* wt2    = (ushort*)(ws + 8388608);          //  ~1 MB: [W;bias;0]^T bf16
    ushort* H      = (ushort*)(ws + 10485760);         //  68.2 MB: aggregated features
    int*    counts = (int*)(ws + 78643200);            // 512 KB
    int*    offs   = (int*)(ws + 79167488);            // 512 KB
    int*    cursor = (int*)(ws + 79691776);            // 512 KB
    int*    sorted = (int*)(ws + 80216064);            //   1 MB

    prep_kernel<<<4480, 256, 0, stream>>>(x, W, bias, xb, wt2, counts);
    hist_kernel<<<1024, 256, 0, stream>>>(etgt, elab, counts);
    scan_kernel<<<NB, 256, 0, stream>>>(counts, offs, cursor, H);
    place_kernel<<<1024, 256, 0, stream>>>(etgt, elab, esrc, cursor, sorted);
    aggregate_kernel<<<32768, 256, 0, stream>>>(xb, counts, offs, sorted, H);
    gemm_kernel<<<dim3(4, 128), 256, 0, stream>>>(H, wt2, out);
}

// Round 4
// 221.617 us; speedup vs baseline: 1.1006x; 1.1006x over previous
//
#include <hip/hip_runtime.h>
#include <stdint.h>

// Problem constants
constexpr int NB = 8;      // batch
constexpr int NS = 2048;   // nodes
constexpr int ND = 256;    // in dim
constexpr int NDO = 256;   // out dim
constexpr int NL = 8;      // labels
constexpr int NE = 32768;  // edges per batch
constexpr int NG = NS * NL;        // groups (t,l) per batch = 16384
constexpr int KH = NL * ND + 32;   // H row length = 2080 (2048 data + 8 cnt + 24 zero pad)

typedef __attribute__((ext_vector_type(8))) short bf16x8;
typedef __attribute__((ext_vector_type(4))) float f32x4;
typedef unsigned int u32;

__device__ __forceinline__ float bf2f(uint32_t u) {
    return __uint_as_float(u << 16);
}
__device__ __forceinline__ uint32_t f2bf(float f) {
    uint32_t x = __float_as_uint(f);
    return (x + 0x7fffu + ((x >> 16) & 1u)) >> 16;
}

// async global->LDS, 16B per lane; lds ptr must be wave-uniform (HW adds lane*16)
__device__ __forceinline__ void gl_lds16(const void* gptr, void* lptr) {
    __builtin_amdgcn_global_load_lds(
        (const __attribute__((address_space(1))) u32*)gptr,
        (__attribute__((address_space(3))) u32*)lptr, 16, 0, 0);
}

// ---- prep: convert x->bf16, build wt2 = [W;bias;0]^T bf16, zero counts ----
__global__ void prep_kernel(const float* __restrict__ x, const float* __restrict__ W,
                            const float* __restrict__ bias,
                            ushort* __restrict__ xb, ushort* __restrict__ wt2,
                            int* __restrict__ counts) {
    int blk = blockIdx.x;
    int tid = threadIdx.x;
    if (blk < 4096) {                       // x f32 -> bf16, 4 elems/thread
        int i = blk * 256 + tid;            // < NB*NS*ND/4
        float4 v = ((const float4*)x)[i];
        ushort4 o;
        o.x = (ushort)f2bf(v.x); o.y = (ushort)f2bf(v.y);
        o.z = (ushort)f2bf(v.z); o.w = (ushort)f2bf(v.w);
        ((ushort4*)xb)[i] = o;
    } else if (blk < 4352) {                // wt2, one block per output column o
        int o = blk - 4096;                 // < 256
        for (int k = tid; k < KH; k += 256) {
            float v = 0.f;
            if (k < NL * ND) v = W[(size_t)k * NDO + o];
            else if (k < NL * ND + NL) v = bias[(k - NL * ND) * NDO + o];
            wt2[(size_t)o * KH + k] = (ushort)f2bf(v);
        }
    } else {                                // zero counts: 131072 ints, int4 stores
        int i = (blk - 4352) * 256 + tid;   // < 32768
        ((int4*)counts)[i] = make_int4(0, 0, 0, 0);
    }
}

// ---- histogram over (b, tgt, label) groups ----
__global__ void hist_kernel(const int* __restrict__ tgt, const int* __restrict__ lab,
                            int* __restrict__ counts) {
    int i = blockIdx.x * blockDim.x + threadIdx.x;   // < NB*NE
    int b = i >> 15;                                  // NE = 32768
    int g = b * NG + tgt[i] * NL + lab[i];
    atomicAdd(&counts[g], 1);
}

// ---- scan phase 1: 128 blocks, each scans 1024 counters (batch-local) ----
__global__ __launch_bounds__(256) void scan1_kernel(const int* __restrict__ counts,
                                                    int* __restrict__ offsets,
                                                    int* __restrict__ bsum) {
    int blk = blockIdx.x;                 // 128 = 8 batches x 16 blocks
    int tid = threadIdx.x;
    int lane = tid & 63, wave = tid >> 6;
    int4 v = ((const int4*)counts)[blk * 256 + tid];
    int s = v.x + v.y + v.z + v.w;
    int incl = s;
    for (int d = 1; d < 64; d <<= 1) {
        int u = __shfl_up(incl, d);
        if (lane >= d) incl += u;
    }
    __shared__ int wsum[4];
    if (lane == 63) wsum[wave] = incl;
    __syncthreads();
    int wbase = 0;
    for (int w = 0; w < wave; w++) wbase += wsum[w];
    int excl = wbase + incl - s;
    int4 o;
    o.x = excl; o.y = o.x + v.x; o.z = o.y + v.y; o.w = o.z + v.z;
    ((int4*)offsets)[blk * 256 + tid] = o;
    if (tid == 255) bsum[blk] = excl + s;
}

// ---- scan phase 2: add per-batch block prefix; write offsets + cursor ----
__global__ __launch_bounds__(256) void scan2_kernel(const int* __restrict__ bsum,
                                                    int* __restrict__ offsets,
                                                    int* __restrict__ cursor) {
    int blk = blockIdx.x;                 // 128
    int tid = threadIdx.x;
    int batch = blk >> 4, idx = blk & 15;
    int base = 0;
    for (int j = 0; j < idx; j++) base += bsum[batch * 16 + j];   // L2-cached, tiny
    int4 o = ((const int4*)offsets)[blk * 256 + tid];
    o.x += base; o.y += base; o.z += base; o.w += base;
    ((int4*)offsets)[blk * 256 + tid] = o;
    ((int4*)cursor)[blk * 256 + tid] = o;
}

// ---- placement: counting-sort edge srcs by (tgt,label) group ----
__global__ void place_kernel(const int* __restrict__ tgt, const int* __restrict__ lab,
                             const int* __restrict__ esrc,
                             int* __restrict__ cursor, int* __restrict__ sorted) {
    int i = blockIdx.x * blockDim.x + threadIdx.x;   // < NB*NE
    int b = i >> 15;
    int g = b * NG + tgt[i] * NL + lab[i];
    int p = atomicAdd(&cursor[g], 1);
    sorted[b * NE + p] = esrc[i];
}

__device__ __forceinline__ void accum4(float4& a, uint2 v) {
    a.x += bf2f(v.x & 0xffffu);
    a.y += bf2f(v.x >> 16);
    a.z += bf2f(v.y & 0xffffu);
    a.w += bf2f(v.y >> 16);
}

// ---- aggregate: one wave per (b,t,l) group; H[b][t][l*256..] = sum of x[src] rows ----
// Also writes the H tail: cnt at col 2048+l (bias fold) and the 24 pad zeros.
__global__ __launch_bounds__(256) void aggregate_kernel(
    const ushort* __restrict__ xb,
    const int* __restrict__ counts, const int* __restrict__ offsets,
    const int* __restrict__ sorted, ushort* __restrict__ H) {
    int g = blockIdx.x * 4 + (threadIdx.x >> 6);     // < NB*NG
    int lane = threadIdx.x & 63;
    int b = g >> 14;                                  // NG = 16384
    int r = g & (NG - 1);
    int t = r >> 3, l = r & (NL - 1);

    int n = counts[g];
    int off = offsets[g];
    const int* srcs = sorted + (size_t)b * NE + off;
    const ushort* xbb = xb + (size_t)b * NS * ND;
    ushort* hrow = H + ((size_t)(b * NS + t)) * KH;

    float4 a0 = {0.f, 0.f, 0.f, 0.f};
    float4 a1 = {0.f, 0.f, 0.f, 0.f};
    for (int base = 0; base < n; base += 64) {
        int m = n - base;
        if (m > 64) m = 64;
        int my = (lane < m) ? srcs[base + lane] : 0;  // lane-parallel index preload
        int k = 0;
        for (; k + 2 <= m; k += 2) {
            int s0 = __shfl(my, k);
            int s1 = __shfl(my, k + 1);
            uint2 v0 = ((const uint2*)(xbb + (size_t)s0 * ND))[lane];
            uint2 v1 = ((const uint2*)(xbb + (size_t)s1 * ND))[lane];
            accum4(a0, v0);
            accum4(a1, v1);
        }
        if (k < m) {
            int s0 = __shfl(my, k);
            uint2 v0 = ((const uint2*)(xbb + (size_t)s0 * ND))[lane];
            accum4(a0, v0);
        }
    }
    a0.x += a1.x; a0.y += a1.y; a0.z += a1.z; a0.w += a1.w;
    uint2 o;
    o.x = f2bf(a0.x) | (f2bf(a0.y) << 16);
    o.y = f2bf(a0.z) | (f2bf(a0.w) << 16);
    ((uint2*)(hrow + l * ND))[lane] = o;
    // tail: count column (bias fold) + pad zeros
    if (lane == 0) hrow[NL * ND + l] = (ushort)f2bf((float)n);
    if (l == 0 && lane < 24) hrow[NL * ND + NL + lane] = 0;
}

// ---- GEMM: out[m][o] = relu( H[m][:] @ wt2[o][:] ), M=16384, N=256, K=2080 ----
// 64x256 tile (full N per block -> H read exactly once), 4 waves each own a
// 64-wide N quarter with 4x4 MFMA 16x16x32 subtiles; m97 staging.
__global__ __launch_bounds__(256) void gemm_kernel(
    const ushort* __restrict__ H, const ushort* __restrict__ wt2,
    float* __restrict__ out) {
    int m0 = blockIdx.x * 64;                  // 256 blocks

    __shared__ ushort As[64 * 32];             //  4 KB
    __shared__ ushort Bs[256 * 32];            // 16 KB

    int tid = threadIdx.x;
    int lane = tid & 63;
    int wave = __builtin_amdgcn_readfirstlane(tid >> 6);
    int ln = lane & 15, quad = lane >> 4;

    f32x4 acc[4][4] = {};

    const ushort* Ag = H + (size_t)m0 * KH;
    int ra = tid >> 2, ca = (tid & 3) << 3;    // chunk coords (row, col*8)

    for (int k0 = 0; k0 < KH; k0 += 32) {
        gl_lds16(Ag + (size_t)ra * KH + k0 + ca, &As[(wave * 64) * 8]);
        for (int p = 0; p < 4; p++)
            gl_lds16(wt2 + (size_t)(p * 64 + ra) * KH + k0 + ca,
                     &Bs[(p * 256 + wave * 64) * 8]);
        __syncthreads();

        bf16x8 af[4], bfr[4];
        for (int i = 0; i < 4; i++)
            af[i] = *(const bf16x8*)&As[(i * 16 + ln) * 32 + quad * 8];
        for (int j = 0; j < 4; j++)
            bfr[j] = *(const bf16x8*)&Bs[(wave * 64 + j * 16 + ln) * 32 + quad * 8];
        for (int i = 0; i < 4; i++)
            for (int j = 0; j < 4; j++)
                acc[i][j] = __builtin_amdgcn_mfma_f32_16x16x32_bf16(af[i], bfr[j], acc[i][j], 0, 0, 0);
        __syncthreads();
    }

    // epilogue: C/D layout col=lane&15, row=quad*4+rr ; fused relu, f32 out
    for (int j = 0; j < 4; j++) {
        int col = wave * 64 + j * 16 + ln;
        for (int i = 0; i < 4; i++) {
            int rbase = m0 + i * 16 + quad * 4;
            for (int rr = 0; rr < 4; rr++) {
                out[(size_t)(rbase + rr) * NDO + col] = fmaxf(acc[i][j][rr], 0.f);
            }
        }
    }
}

extern "C" void kernel_launch(void* const* d_in, const int* in_sizes, int n_in,
                              void* d_out, int out_size, void* d_ws, size_t ws_size,
                              hipStream_t stream) {
    const float* x    = (const float*)d_in[0];
    const int*   esrc = (const int*)d_in[1];
    const int*   etgt = (const int*)d_in[2];
    const int*   elab = (const int*)d_in[3];
    const float* W    = (const float*)d_in[4];
    const float* bias = (const float*)d_in[5];
    float* out = (float*)d_out;

    char* ws = (char*)d_ws;
    ushort* xb     = (ushort*)(ws);                    //  8 MB: x bf16
    ushort* wt2    = (ushort*)(ws + 8388608);          //  ~1 MB: [W;bias;0]^T bf16
    ushort* H      = (ushort*)(ws + 10485760);         //  68.2 MB: aggregated features
    int*    counts = (int*)(ws + 78643200);            // 512 KB
    int*    offs   = (int*)(ws + 79167488);            // 512 KB
    int*    cursor = (int*)(ws + 79691776);            // 512 KB
    int*    sorted = (int*)(ws + 80216064);            //   1 MB
    int*    bsum   = (int*)(ws + 81264640);            // 512 B

    prep_kernel<<<4480, 256, 0, stream>>>(x, W, bias, xb, wt2, counts);
    hist_kernel<<<1024, 256, 0, stream>>>(etgt, elab, counts);
    scan1_kernel<<<128, 256, 0, stream>>>(counts, offs, bsum);
    scan2_kernel<<<128, 256, 0, stream>>>(bsum, offs, cursor);
    place_kernel<<<1024, 256, 0, stream>>>(etgt, elab, esrc, cursor, sorted);
    aggregate_kernel<<<32768, 256, 0, stream>>>(xb, counts, offs, sorted, H);
    gemm_kernel<<<256, 256, 0, stream>>>(H, wt2, out);
}

// Round 5
// 195.350 us; speedup vs baseline: 1.2486x; 1.1345x over previous
//
#include <hip/hip_runtime.h>
#include <stdint.h>

// Problem constants
constexpr int NB = 8;      // batch
constexpr int NS = 2048;   // nodes
constexpr int ND = 256;    // in dim
constexpr int NDO = 256;   // out dim
constexpr int NL = 8;      // labels
constexpr int NE = 32768;  // edges per batch
constexpr int NG = NS * NL;        // groups (t,l) per batch = 16384
constexpr int KH = NL * ND + 32;   // H row length = 2080 (2048 data + 8 cnt + 24 zero pad)

typedef __attribute__((ext_vector_type(8))) short bf16x8;
typedef __attribute__((ext_vector_type(4))) float f32x4;
typedef unsigned int u32;

__device__ __forceinline__ float bf2f(uint32_t u) {
    return __uint_as_float(u << 16);
}
__device__ __forceinline__ uint32_t f2bf(float f) {
    uint32_t x = __float_as_uint(f);
    return (x + 0x7fffu + ((x >> 16) & 1u)) >> 16;
}

// async global->LDS, 16B per lane; lds ptr must be wave-uniform (HW adds lane*16)
__device__ __forceinline__ void gl_lds16(const void* gptr, void* lptr) {
    __builtin_amdgcn_global_load_lds(
        (const __attribute__((address_space(1))) u32*)gptr,
        (__attribute__((address_space(3))) u32*)lptr, 16, 0, 0);
}

// ---- prep: convert x->bf16, build wt2 = [W;bias;0]^T bf16, zero counts ----
__global__ void prep_kernel(const float* __restrict__ x, const float* __restrict__ W,
                            const float* __restrict__ bias,
                            ushort* __restrict__ xb, ushort* __restrict__ wt2,
                            int* __restrict__ counts) {
    int blk = blockIdx.x;
    int tid = threadIdx.x;
    if (blk < 4096) {                       // x f32 -> bf16, 4 elems/thread
        int i = blk * 256 + tid;            // < NB*NS*ND/4
        float4 v = ((const float4*)x)[i];
        ushort4 o;
        o.x = (ushort)f2bf(v.x); o.y = (ushort)f2bf(v.y);
        o.z = (ushort)f2bf(v.z); o.w = (ushort)f2bf(v.w);
        ((ushort4*)xb)[i] = o;
    } else if (blk < 4352) {                // wt2, one block per output column o
        int o = blk - 4096;                 // < 256
        for (int k = tid; k < KH; k += 256) {
            float v = 0.f;
            if (k < NL * ND) v = W[(size_t)k * NDO + o];
            else if (k < NL * ND + NL) v = bias[(k - NL * ND) * NDO + o];
            wt2[(size_t)o * KH + k] = (ushort)f2bf(v);
        }
    } else {                                // zero counts: 131072 ints, int4 stores
        int i = (blk - 4352) * 256 + tid;   // < 32768
        ((int4*)counts)[i] = make_int4(0, 0, 0, 0);
    }
}

// ---- histogram over (b, tgt, label) groups ----
__global__ void hist_kernel(const int* __restrict__ tgt, const int* __restrict__ lab,
                            int* __restrict__ counts) {
    int i = blockIdx.x * blockDim.x + threadIdx.x;   // < NB*NE
    int b = i >> 15;                                  // NE = 32768
    int g = b * NG + tgt[i] * NL + lab[i];
    atomicAdd(&counts[g], 1);
}

// ---- scan phase 1: 128 blocks, each scans 1024 counters (batch-local) ----
__global__ __launch_bounds__(256) void scan1_kernel(const int* __restrict__ counts,
                                                    int* __restrict__ offsets,
                                                    int* __restrict__ bsum) {
    int blk = blockIdx.x;                 // 128 = 8 batches x 16 blocks
    int tid = threadIdx.x;
    int lane = tid & 63, wave = tid >> 6;
    int4 v = ((const int4*)counts)[blk * 256 + tid];
    int s = v.x + v.y + v.z + v.w;
    int incl = s;
    for (int d = 1; d < 64; d <<= 1) {
        int u = __shfl_up(incl, d);
        if (lane >= d) incl += u;
    }
    __shared__ int wsum[4];
    if (lane == 63) wsum[wave] = incl;
    __syncthreads();
    int wbase = 0;
    for (int w = 0; w < wave; w++) wbase += wsum[w];
    int excl = wbase + incl - s;
    int4 o;
    o.x = excl; o.y = o.x + v.x; o.z = o.y + v.y; o.w = o.z + v.z;
    ((int4*)offsets)[blk * 256 + tid] = o;
    if (tid == 255) bsum[blk] = excl + s;
}

// ---- scan phase 2: add per-batch block prefix; write offsets + cursor ----
__global__ __launch_bounds__(256) void scan2_kernel(const int* __restrict__ bsum,
                                                    int* __restrict__ offsets,
                                                    int* __restrict__ cursor) {
    int blk = blockIdx.x;                 // 128
    int tid = threadIdx.x;
    int batch = blk >> 4, idx = blk & 15;
    int base = 0;
    for (int j = 0; j < idx; j++) base += bsum[batch * 16 + j];   // L2-cached, tiny
    int4 o = ((const int4*)offsets)[blk * 256 + tid];
    o.x += base; o.y += base; o.z += base; o.w += base;
    ((int4*)offsets)[blk * 256 + tid] = o;
    ((int4*)cursor)[blk * 256 + tid] = o;
}

// ---- placement: counting-sort edge srcs by (tgt,label) group ----
__global__ void place_kernel(const int* __restrict__ tgt, const int* __restrict__ lab,
                             const int* __restrict__ esrc,
                             int* __restrict__ cursor, int* __restrict__ sorted) {
    int i = blockIdx.x * blockDim.x + threadIdx.x;   // < NB*NE
    int b = i >> 15;
    int g = b * NG + tgt[i] * NL + lab[i];
    int p = atomicAdd(&cursor[g], 1);
    sorted[b * NE + p] = esrc[i];
}

__device__ __forceinline__ void accum4(float4& a, uint2 v) {
    a.x += bf2f(v.x & 0xffffu);
    a.y += bf2f(v.x >> 16);
    a.z += bf2f(v.y & 0xffffu);
    a.w += bf2f(v.y >> 16);
}

// ---- aggregate: one wave per (b,t,l) group; H[b][t][l*256..] = sum of x[src] rows ----
// Also writes the H tail: cnt at col 2048+l (bias fold) and the 24 pad zeros.
__global__ __launch_bounds__(256) void aggregate_kernel(
    const ushort* __restrict__ xb,
    const int* __restrict__ counts, const int* __restrict__ offsets,
    const int* __restrict__ sorted, ushort* __restrict__ H) {
    int g = blockIdx.x * 4 + (threadIdx.x >> 6);     // < NB*NG
    int lane = threadIdx.x & 63;
    int b = g >> 14;                                  // NG = 16384
    int r = g & (NG - 1);
    int t = r >> 3, l = r & (NL - 1);

    int n = counts[g];
    int off = offsets[g];
    const int* srcs = sorted + (size_t)b * NE + off;
    const ushort* xbb = xb + (size_t)b * NS * ND;
    ushort* hrow = H + ((size_t)(b * NS + t)) * KH;

    float4 a0 = {0.f, 0.f, 0.f, 0.f};
    float4 a1 = {0.f, 0.f, 0.f, 0.f};
    for (int base = 0; base < n; base += 64) {
        int m = n - base;
        if (m > 64) m = 64;
        int my = (lane < m) ? srcs[base + lane] : 0;  // lane-parallel index preload
        int k = 0;
        for (; k + 2 <= m; k += 2) {
            int s0 = __shfl(my, k);
            int s1 = __shfl(my, k + 1);
            uint2 v0 = ((const uint2*)(xbb + (size_t)s0 * ND))[lane];
            uint2 v1 = ((const uint2*)(xbb + (size_t)s1 * ND))[lane];
            accum4(a0, v0);
            accum4(a1, v1);
        }
        if (k < m) {
            int s0 = __shfl(my, k);
            uint2 v0 = ((const uint2*)(xbb + (size_t)s0 * ND))[lane];
            accum4(a0, v0);
        }
    }
    a0.x += a1.x; a0.y += a1.y; a0.z += a1.z; a0.w += a1.w;
    uint2 o;
    o.x = f2bf(a0.x) | (f2bf(a0.y) << 16);
    o.y = f2bf(a0.z) | (f2bf(a0.w) << 16);
    ((uint2*)(hrow + l * ND))[lane] = o;
    // tail: count column (bias fold) + pad zeros
    if (lane == 0) hrow[NL * ND + l] = (ushort)f2bf((float)n);
    if (l == 0 && lane < 24) hrow[NL * ND + NL + lane] = 0;
}

// ---- GEMM: out[m][o] = relu( H[m][:] @ wt2[o][:] ), M=16384, N=256, K=2080 ----
// 64x128 tile, grid (2,256)=512 blocks -> 2 blocks/CU so barrier drains overlap
// across blocks. 4 waves in 2x2, each wave 32x64 = 2x4 MFMA subtiles.
__global__ __launch_bounds__(256) void gemm_kernel(
    const ushort* __restrict__ H, const ushort* __restrict__ wt2,
    float* __restrict__ out) {
    int n0 = blockIdx.x * 128;                 // N tile (2)
    int m0 = blockIdx.y * 64;                  // M tile (256)

    __shared__ ushort As[64 * 32];             //  4 KB
    __shared__ ushort Bs[128 * 32];            //  8 KB

    int tid = threadIdx.x;
    int lane = tid & 63;
    int wave = __builtin_amdgcn_readfirstlane(tid >> 6);
    int wm = wave & 1, wn = wave >> 1;
    int ln = lane & 15, quad = lane >> 4;

    f32x4 acc[2][4] = {};

    const ushort* Ag = H + (size_t)m0 * KH;
    const ushort* Bg = wt2 + (size_t)n0 * KH;
    int ra = tid >> 2, ca = (tid & 3) << 3;    // chunk coords (row, col*8)

    for (int k0 = 0; k0 < KH; k0 += 32) {
        gl_lds16(Ag + (size_t)ra * KH + k0 + ca, &As[(wave * 64) * 8]);
        gl_lds16(Bg + (size_t)ra * KH + k0 + ca, &Bs[(wave * 64) * 8]);
        gl_lds16(Bg + (size_t)(ra + 64) * KH + k0 + ca, &Bs[(256 + wave * 64) * 8]);
        __syncthreads();

        bf16x8 af[2], bfr[4];
        for (int i = 0; i < 2; i++)
            af[i] = *(const bf16x8*)&As[(wm * 32 + i * 16 + ln) * 32 + quad * 8];
        for (int j = 0; j < 4; j++)
            bfr[j] = *(const bf16x8*)&Bs[(wn * 64 + j * 16 + ln) * 32 + quad * 8];
        for (int i = 0; i < 2; i++)
            for (int j = 0; j < 4; j++)
                acc[i][j] = __builtin_amdgcn_mfma_f32_16x16x32_bf16(af[i], bfr[j], acc[i][j], 0, 0, 0);
        __syncthreads();
    }

    // epilogue: C/D layout col=lane&15, row=quad*4+rr ; fused relu, f32 out
    for (int j = 0; j < 4; j++) {
        int col = n0 + wn * 64 + j * 16 + ln;
        for (int i = 0; i < 2; i++) {
            int rbase = m0 + wm * 32 + i * 16 + quad * 4;
            for (int rr = 0; rr < 4; rr++) {
                out[(size_t)(rbase + rr) * NDO + col] = fmaxf(acc[i][j][rr], 0.f);
            }
        }
    }
}

extern "C" void kernel_launch(void* const* d_in, const int* in_sizes, int n_in,
                              void* d_out, int out_size, void* d_ws, size_t ws_size,
                              hipStream_t stream) {
    const float* x    = (const float*)d_in[0];
    const int*   esrc = (const int*)d_in[1];
    const int*   etgt = (const int*)d_in[2];
    const int*   elab = (const int*)d_in[3];
    const float* W    = (const float*)d_in[4];
    const float* bias = (const float*)d_in[5];
    float* out = (float*)d_out;

    char* ws = (char*)d_ws;
    ushort* xb     = (ushort*)(ws);                    //  8 MB: x bf16
    ushort* wt2    = (ushort*)(ws + 8388608);          //  ~1 MB: [W;bias;0]^T bf16
    ushort* H      = (ushort*)(ws + 10485760);         //  68.2 MB: aggregated features
    int*    counts = (int*)(ws + 78643200);            // 512 KB
    int*    offs   = (int*)(ws + 79167488);            // 512 KB
    int*    cursor = (int*)(ws + 79691776);            // 512 KB
    int*    sorted = (int*)(ws + 80216064);            //   1 MB
    int*    bsum   = (int*)(ws + 81264640);            // 512 B

    prep_kernel<<<4480, 256, 0, stream>>>(x, W, bias, xb, wt2, counts);
    hist_kernel<<<1024, 256, 0, stream>>>(etgt, elab, counts);
    scan1_kernel<<<128, 256, 0, stream>>>(counts, offs, bsum);
    scan2_kernel<<<128, 256, 0, stream>>>(bsum, offs, cursor);
    place_kernel<<<1024, 256, 0, stream>>>(etgt, elab, esrc, cursor, sorted);
    aggregate_kernel<<<32768, 256, 0, stream>>>(xb, counts, offs, sorted, H);
    gemm_kernel<<<dim3(2, 256), 256, 0, stream>>>(H, wt2, out);
}

// Round 6
// 185.616 us; speedup vs baseline: 1.3140x; 1.0524x over previous
//
#include <hip/hip_runtime.h>
#include <stdint.h>

// Problem constants
constexpr int NB = 8;      // batch
constexpr int NS = 2048;   // nodes
constexpr int ND = 256;    // in dim
constexpr int NDO = 256;   // out dim
constexpr int NL = 8;      // labels
constexpr int NE = 32768;  // edges per batch
constexpr int NG = NS * NL;        // groups (t,l) per batch = 16384
constexpr int KH = 2112;           // H row: 2048 data + 8 cnt + 56 zero (mult of 64)

typedef __attribute__((ext_vector_type(8))) short bf16x8;
typedef __attribute__((ext_vector_type(4))) float f32x4;
typedef unsigned int u32;

__device__ __forceinline__ float bf2f(uint32_t u) {
    return __uint_as_float(u << 16);
}
__device__ __forceinline__ uint32_t f2bf(float f) {
    uint32_t x = __float_as_uint(f);
    return (x + 0x7fffu + ((x >> 16) & 1u)) >> 16;
}

// async global->LDS, 16B per lane; lds ptr must be wave-uniform (HW adds lane*16)
__device__ __forceinline__ void gl_lds16(const void* gptr, void* lptr) {
    __builtin_amdgcn_global_load_lds(
        (const __attribute__((address_space(1))) u32*)gptr,
        (__attribute__((address_space(3))) u32*)lptr, 16, 0, 0);
}

// ---- prep: convert x->bf16, build wt2 = [W;bias;0]^T bf16, zero counts ----
__global__ void prep_kernel(const float* __restrict__ x, const float* __restrict__ W,
                            const float* __restrict__ bias,
                            ushort* __restrict__ xb, ushort* __restrict__ wt2,
                            int* __restrict__ counts) {
    int blk = blockIdx.x;
    int tid = threadIdx.x;
    if (blk < 4096) {                       // x f32 -> bf16, 4 elems/thread
        int i = blk * 256 + tid;            // < NB*NS*ND/4
        float4 v = ((const float4*)x)[i];
        ushort4 o;
        o.x = (ushort)f2bf(v.x); o.y = (ushort)f2bf(v.y);
        o.z = (ushort)f2bf(v.z); o.w = (ushort)f2bf(v.w);
        ((ushort4*)xb)[i] = o;
    } else if (blk < 4352) {                // wt2, one block per output column o
        int o = blk - 4096;                 // < 256
        for (int k = tid; k < KH; k += 256) {
            float v = 0.f;
            if (k < NL * ND) v = W[(size_t)k * NDO + o];
            else if (k < NL * ND + NL) v = bias[(k - NL * ND) * NDO + o];
            wt2[(size_t)o * KH + k] = (ushort)f2bf(v);
        }
    } else {                                // zero counts: 131072 ints, int4 stores
        int i = (blk - 4352) * 256 + tid;   // < 32768
        ((int4*)counts)[i] = make_int4(0, 0, 0, 0);
    }
}

// ---- histogram over (b, tgt, label) groups ----
__global__ void hist_kernel(const int* __restrict__ tgt, const int* __restrict__ lab,
                            int* __restrict__ counts) {
    int i = blockIdx.x * blockDim.x + threadIdx.x;   // < NB*NE
    int b = i >> 15;                                  // NE = 32768
    int g = b * NG + tgt[i] * NL + lab[i];
    atomicAdd(&counts[g], 1);
}

// ---- scan phase 1: 128 blocks, each scans 1024 counters (batch-local) ----
__global__ __launch_bounds__(256) void scan1_kernel(const int* __restrict__ counts,
                                                    int* __restrict__ offsets,
                                                    int* __restrict__ bsum) {
    int blk = blockIdx.x;                 // 128 = 8 batches x 16 blocks
    int tid = threadIdx.x;
    int lane = tid & 63, wave = tid >> 6;
    int4 v = ((const int4*)counts)[blk * 256 + tid];
    int s = v.x + v.y + v.z + v.w;
    int incl = s;
    for (int d = 1; d < 64; d <<= 1) {
        int u = __shfl_up(incl, d);
        if (lane >= d) incl += u;
    }
    __shared__ int wsum[4];
    if (lane == 63) wsum[wave] = incl;
    __syncthreads();
    int wbase = 0;
    for (int w = 0; w < wave; w++) wbase += wsum[w];
    int excl = wbase + incl - s;
    int4 o;
    o.x = excl; o.y = o.x + v.x; o.z = o.y + v.y; o.w = o.z + v.z;
    ((int4*)offsets)[blk * 256 + tid] = o;
    if (tid == 255) bsum[blk] = excl + s;
}

// ---- scan phase 2: add per-batch block prefix; write offsets + cursor ----
__global__ __launch_bounds__(256) void scan2_kernel(const int* __restrict__ bsum,
                                                    int* __restrict__ offsets,
                                                    int* __restrict__ cursor) {
    int blk = blockIdx.x;                 // 128
    int tid = threadIdx.x;
    int batch = blk >> 4, idx = blk & 15;
    int base = 0;
    for (int j = 0; j < idx; j++) base += bsum[batch * 16 + j];   // L2-cached, tiny
    int4 o = ((const int4*)offsets)[blk * 256 + tid];
    o.x += base; o.y += base; o.z += base; o.w += base;
    ((int4*)offsets)[blk * 256 + tid] = o;
    ((int4*)cursor)[blk * 256 + tid] = o;
}

// ---- placement: counting-sort edge srcs by (tgt,label) group ----
__global__ void place_kernel(const int* __restrict__ tgt, const int* __restrict__ lab,
                             const int* __restrict__ esrc,
                             int* __restrict__ cursor, int* __restrict__ sorted) {
    int i = blockIdx.x * blockDim.x + threadIdx.x;   // < NB*NE
    int b = i >> 15;
    int g = b * NG + tgt[i] * NL + lab[i];
    int p = atomicAdd(&cursor[g], 1);
    sorted[b * NE + p] = esrc[i];
}

__device__ __forceinline__ void accum4(float4& a, uint2 v) {
    a.x += bf2f(v.x & 0xffffu);
    a.y += bf2f(v.x >> 16);
    a.z += bf2f(v.y & 0xffffu);
    a.w += bf2f(v.y >> 16);
}

// ---- aggregate: one wave per (b,t,l) group; H[b][t][l*256..] = sum of x[src] rows ----
// Also writes the H tail: cnt at col 2048+l (bias fold) and the 56 pad zeros.
__global__ __launch_bounds__(256) void aggregate_kernel(
    const ushort* __restrict__ xb,
    const int* __restrict__ counts, const int* __restrict__ offsets,
    const int* __restrict__ sorted, ushort* __restrict__ H) {
    int g = blockIdx.x * 4 + (threadIdx.x >> 6);     // < NB*NG
    int lane = threadIdx.x & 63;
    int b = g >> 14;                                  // NG = 16384
    int r = g & (NG - 1);
    int t = r >> 3, l = r & (NL - 1);

    int n = counts[g];
    int off = offsets[g];
    const int* srcs = sorted + (size_t)b * NE + off;
    const ushort* xbb = xb + (size_t)b * NS * ND;
    ushort* hrow = H + ((size_t)(b * NS + t)) * KH;

    float4 a0 = {0.f, 0.f, 0.f, 0.f};
    float4 a1 = {0.f, 0.f, 0.f, 0.f};
    for (int base = 0; base < n; base += 64) {
        int m = n - base;
        if (m > 64) m = 64;
        int my = (lane < m) ? srcs[base + lane] : 0;  // lane-parallel index preload
        int k = 0;
        for (; k + 2 <= m; k += 2) {
            int s0 = __shfl(my, k);
            int s1 = __shfl(my, k + 1);
            uint2 v0 = ((const uint2*)(xbb + (size_t)s0 * ND))[lane];
            uint2 v1 = ((const uint2*)(xbb + (size_t)s1 * ND))[lane];
            accum4(a0, v0);
            accum4(a1, v1);
        }
        if (k < m) {
            int s0 = __shfl(my, k);
            uint2 v0 = ((const uint2*)(xbb + (size_t)s0 * ND))[lane];
            accum4(a0, v0);
        }
    }
    a0.x += a1.x; a0.y += a1.y; a0.z += a1.z; a0.w += a1.w;
    uint2 o;
    o.x = f2bf(a0.x) | (f2bf(a0.y) << 16);
    o.y = f2bf(a0.z) | (f2bf(a0.w) << 16);
    ((uint2*)(hrow + l * ND))[lane] = o;
    // tail: count column (bias fold) + pad zeros
    if (lane == 0) hrow[NL * ND + l] = (ushort)f2bf((float)n);
    if (l == 0 && lane < 56) hrow[NL * ND + NL + lane] = 0;
}

// ---- GEMM: out[m][o] = relu( H[m][:] @ wt2[o][:] ), M=16384, N=256, K=2112 ----
// 64x128 tile, grid (2,256)=512 -> 2 blocks/CU. BK=64: 16 MFMA/wave per barrier.
// LDS: 16B chunk c of row r lives at slot r*8 + (c ^ (r&7)) -> fragment reads are
// 2-way bank aliased only (free); global_load_lds writes stay lane-contiguous.
__global__ __launch_bounds__(256) void gemm_kernel(
    const ushort* __restrict__ H, const ushort* __restrict__ wt2,
    float* __restrict__ out) {
    int n0 = blockIdx.x * 128;                 // N tile (2)
    int m0 = blockIdx.y * 64;                  // M tile (256)

    __shared__ ushort As[64 * 64];             //  8 KB (512 slots)
    __shared__ ushort Bs[128 * 64];            // 16 KB (1024 slots)

    int tid = threadIdx.x;
    int lane = tid & 63;
    int wave = __builtin_amdgcn_readfirstlane(tid >> 6);
    int wm = wave & 1, wn = wave >> 1;
    int ln = lane & 15, quad = lane >> 4;

    f32x4 acc[2][4] = {};

    const ushort* Ag = H + (size_t)m0 * KH;
    const ushort* Bg = wt2 + (size_t)n0 * KH;

    // precompute per-lane staging coords: slot s -> row r=s>>3, chunk cg=(s&7)^(r&7)
    int sa0 = wave * 128 + lane;               // As pass 0 slot (pass 1: +64)
    int sb0 = wave * 256 + lane;               // Bs pass 0 slot (passes: +64p)

    for (int k0 = 0; k0 < KH; k0 += 64) {
        for (int p = 0; p < 2; p++) {
            int s = sa0 + p * 64;
            int r = s >> 3, cg = (s & 7) ^ (r & 7);
            gl_lds16(Ag + (size_t)r * KH + k0 + cg * 8, &As[(wave * 128 + p * 64) * 8]);
        }
        for (int p = 0; p < 4; p++) {
            int s = sb0 + p * 64;
            int r = s >> 3, cg = (s & 7) ^ (r & 7);
            gl_lds16(Bg + (size_t)r * KH + k0 + cg * 8, &Bs[(wave * 256 + p * 64) * 8]);
        }
        __syncthreads();

        for (int h = 0; h < 2; h++) {          // two K=32 halves of the BK=64 tile
            bf16x8 af[2], bfr[4];
            for (int i = 0; i < 2; i++) {
                int r = wm * 32 + i * 16 + ln;
                int c = (h * 4 + quad) ^ (r & 7);
                af[i] = *(const bf16x8*)&As[(r * 8 + c) * 8];
            }
            for (int j = 0; j < 4; j++) {
                int r = wn * 64 + j * 16 + ln;
                int c = (h * 4 + quad) ^ (r & 7);
                bfr[j] = *(const bf16x8*)&Bs[(r * 8 + c) * 8];
            }
            for (int i = 0; i < 2; i++)
                for (int j = 0; j < 4; j++)
                    acc[i][j] = __builtin_amdgcn_mfma_f32_16x16x32_bf16(af[i], bfr[j], acc[i][j], 0, 0, 0);
        }
        __syncthreads();
    }

    // epilogue: C/D layout col=lane&15, row=quad*4+rr ; fused relu, f32 out
    for (int j = 0; j < 4; j++) {
        int col = n0 + wn * 64 + j * 16 + ln;
        for (int i = 0; i < 2; i++) {
            int rbase = m0 + wm * 32 + i * 16 + quad * 4;
            for (int rr = 0; rr < 4; rr++) {
                out[(size_t)(rbase + rr) * NDO + col] = fmaxf(acc[i][j][rr], 0.f);
            }
        }
    }
}

extern "C" void kernel_launch(void* const* d_in, const int* in_sizes, int n_in,
                              void* d_out, int out_size, void* d_ws, size_t ws_size,
                              hipStream_t stream) {
    const float* x    = (const float*)d_in[0];
    const int*   esrc = (const int*)d_in[1];
    const int*   etgt = (const int*)d_in[2];
    const int*   elab = (const int*)d_in[3];
    const float* W    = (const float*)d_in[4];
    const float* bias = (const float*)d_in[5];
    float* out = (float*)d_out;

    char* ws = (char*)d_ws;
    ushort* xb     = (ushort*)(ws);                    //  8 MB: x bf16
    ushort* wt2    = (ushort*)(ws + 8388608);          //  ~1.03 MB: [W;bias;0]^T bf16
    ushort* H      = (ushort*)(ws + 10485760);         //  69.2 MB: aggregated features
    int*    counts = (int*)(ws + 79691776);            // 512 KB
    int*    offs   = (int*)(ws + 80216064);            // 512 KB
    int*    cursor = (int*)(ws + 80740352);            // 512 KB
    int*    sorted = (int*)(ws + 81264640);            //   1 MB
    int*    bsum   = (int*)(ws + 82313216);            // 512 B

    prep_kernel<<<4480, 256, 0, stream>>>(x, W, bias, xb, wt2, counts);
    hist_kernel<<<1024, 256, 0, stream>>>(etgt, elab, counts);
    scan1_kernel<<<128, 256, 0, stream>>>(counts, offs, bsum);
    scan2_kernel<<<128, 256, 0, stream>>>(bsum, offs, cursor);
    place_kernel<<<1024, 256, 0, stream>>>(etgt, elab, esrc, cursor, sorted);
    aggregate_kernel<<<32768, 256, 0, stream>>>(xb, counts, offs, sorted, H);
    gemm_kernel<<<dim3(2, 256), 256, 0, stream>>>(H, wt2, out);
}